// Round 9
// baseline (179.579 us; speedup 1.0000x reference)
//
#include <hip/hip_runtime.h>
#include <hip/hip_cooperative_groups.h>
#include <math.h>
#include <stdint.h>

#define BATCH 8192
#define NI    8
#define NM    3
#define NT    243             // K-steps; step t = digits d0..d4, 27 rules (+5 zero pads)
#define IL2C  (-0.72134752f)  // -0.5*log2(e): mu = exp2(d*d*IL2C/sigma^2)

namespace cg = cooperative_groups;

typedef uint32_t u32;
typedef __fp16 h2    __attribute__((ext_vector_type(2)));
typedef __fp16 f16x8 __attribute__((ext_vector_type(8)));
typedef float  f32x4 __attribute__((ext_vector_type(4)));
typedef u32    u32x4 __attribute__((ext_vector_type(4)));

__device__ __forceinline__ u32 pack2(float a, float b) {
    h2 p = __builtin_amdgcn_cvt_pkrtz(a, b);
    return __builtin_bit_cast(u32, p);
}
__device__ __forceinline__ float sel3(const float* v, int i) {
    return (i == 0) ? v[0] : ((i == 1) ? v[1] : v[2]);
}

// standalone prep (fallback path only) — same math as fused phase 1
__global__ __launch_bounds__(256) void sugeno_prep(
    const float* __restrict__ cons, u32* __restrict__ Bpack)
{
    int idx = blockIdx.x * 256 + threadIdx.x;
    if (idx >= NT * 64) return;
    int t = idx >> 6, l = idx & 63, n = l & 15, kb = (l >> 4) * 8;
    u32 w[4];
    #pragma unroll
    for (int p = 0; p < 4; ++p) {
        int k0 = kb + 2 * p, k1 = k0 + 1;
        float f0 = (k0 < 27 && n < 9) ? cons[(size_t)(t * 27 + k0) * 9 + n] : 0.0f;
        float f1 = (k1 < 27 && n < 9) ? cons[(size_t)(t * 27 + k1) * 9 + n] : 0.0f;
        w[p] = pack2(f0, f1);
    }
    u32x4 ww; ww[0] = w[0]; ww[1] = w[1]; ww[2] = w[2]; ww[3] = w[3];
    ((u32x4*)Bpack)[idx] = ww;
}

// Fused: [pack B -> fence -> grid sync ->] GEMM + epilogue.
// coop=1: cooperative single-kernel. coop=0: Bpack already valid (prep ran).
__global__ __launch_bounds__(512, 4) void sugeno_fused(
    const float* __restrict__ x,        // [BATCH][8]
    const float* __restrict__ centers,  // [8][3]
    const float* __restrict__ sigmas,   // [3]
    const float* __restrict__ cons,     // [6561][9]
    u32*         __restrict__ Bpack,    // [NT*64] u32x4
    float* __restrict__ out,            // [BATCH]
    int coop)
{
    __shared__ float Wred[8][256];
    const int tid  = threadIdx.x;
    const int l    = tid & 63;
    const int wv   = tid >> 6;          // 0..7
    const int tile = blockIdx.x;
    const int brow = tile * 16 + (l & 15);

    // ---- phase 1: pack B (grid-strided once; only first 31 blocks work) ----
    if (coop) {
        int idx = blockIdx.x * 512 + tid;
        if (idx < NT * 64) {
            int t = idx >> 6, ll = idx & 63, n = ll & 15, kb2 = (ll >> 4) * 8;
            u32 w[4];
            #pragma unroll
            for (int p = 0; p < 4; ++p) {
                int k0 = kb2 + 2 * p, k1 = k0 + 1;
                float f0 = (k0 < 27 && n < 9) ? cons[(size_t)(t * 27 + k0) * 9 + n] : 0.0f;
                float f1 = (k1 < 27 && n < 9) ? cons[(size_t)(t * 27 + k1) * 9 + n] : 0.0f;
                w[p] = pack2(f0, f1);
            }
            u32x4 ww; ww[0] = w[0]; ww[1] = w[1]; ww[2] = w[2]; ww[3] = w[3];
            ((u32x4*)Bpack)[idx] = ww;
        }
    }

    // ---- prologue (independent of Bpack — hides pack latency) ----
    const float4* xv = (const float4*)(x + (size_t)brow * NI);
    float4 x0 = xv[0], x1 = xv[1];
    float xr[NI] = {x0.x, x0.y, x0.z, x0.w, x1.x, x1.y, x1.z, x1.w};

    float il2[NM];
    #pragma unroll
    for (int m = 0; m < NM; ++m) {
        float s = sigmas[m];
        il2[m] = IL2C / (s * s);
    }

    // normalized memberships mA[j][m] = exp2(a_jm - max_m a_jm) in (0,1]
    float mA[NI][NM];
    #pragma unroll
    for (int j = 0; j < NI; ++j) {
        float d0 = xr[j] - centers[j * NM + 0];
        float d1 = xr[j] - centers[j * NM + 1];
        float d2 = xr[j] - centers[j * NM + 2];
        float a0 = d0 * d0 * il2[0];
        float a1 = d1 * d1 * il2[1];
        float a2 = d2 * d2 * il2[2];
        float Kj = fmaxf(fmaxf(a0, a1), a2);
        mA[j][0] = exp2f(a0 - Kj);
        mA[j][1] = exp2f(a1 - Kj);
        mA[j][2] = exp2f(a2 - Kj);
    }

    // per-lane low-digit products, packed f16 pairs
    const int kb = (l >> 4) * 8;
    u32 Lp[4];
    #pragma unroll
    for (int i = 0; i < 4; ++i) {
        float lv[2];
        #pragma unroll
        for (int h = 0; h < 2; ++h) {
            int k = kb + 2 * i + h;
            lv[h] = (k < 27)
                  ? sel3(mA[5], k / 9) * sel3(mA[6], (k % 9) / 3) * sel3(mA[7], k % 3)
                  : 0.0f;
        }
        Lp[i] = pack2(lv[0], lv[1]);
    }

    const int t0     = wv * 30;
    const int ngroup = (wv == 7) ? 11 : 10;

    int g3 = t0 / 3;
    int d3 = g3 % 3, d2 = (g3 / 3) % 3, d1 = (g3 / 9) % 3, d0 = g3 / 27;
    float P3 = sel3(mA[0], d0) * sel3(mA[1], d1) * sel3(mA[2], d2) * sel3(mA[3], d3);

    // ---- barrier: Bpack visible to all XCDs ----
    if (coop) {
        __threadfence();                 // agent-scope release (L2 writeback)
        cg::this_grid().sync();
        __threadfence();                 // acquire (invalidate stale lines)
    }

    // ---- GEMM phase: prefetch depth 2 ----
    const u32x4* bp = (const u32x4*)Bpack + (size_t)t0 * 64 + l;

    f32x4 acc = {0.0f, 0.0f, 0.0f, 0.0f};
    u32x4 c0 = bp[0],   c1 = bp[64],  c2 = bp[128];
    u32x4 n0 = bp[192], n1 = bp[256], n2 = bp[320];

    for (int g = 0; g < ngroup; ++g) {
        u32x4 f0 = {}, f1 = {}, f2 = {};
        if (g + 2 < ngroup) {
            const u32x4* fb = bp + (size_t)(g + 2) * 192;
            f0 = fb[0]; f1 = fb[64]; f2 = fb[128];
        }
        #pragma unroll
        for (int ph = 0; ph < 3; ++ph) {        // d4 = ph (compile-time)
            float U = P3 * mA[4][ph];
            u32 uu = pack2(U, U);
            h2 uh = __builtin_bit_cast(h2, uu);
            u32x4 aw;
            #pragma unroll
            for (int i = 0; i < 4; ++i) {
                h2 prod = __builtin_bit_cast(h2, Lp[i]) * uh;   // v_pk_mul_f16
                aw[i] = __builtin_bit_cast(u32, prod);
            }
            u32x4 bw = (ph == 0) ? c0 : (ph == 1) ? c1 : c2;
            acc = __builtin_amdgcn_mfma_f32_16x16x32_f16(
                      __builtin_bit_cast(f16x8, aw),
                      __builtin_bit_cast(f16x8, bw),
                      acc, 0, 0, 0);
        }
        c0 = n0; c1 = n1; c2 = n2;
        n0 = f0; n1 = f1; n2 = f2;
        if (++d3 == 3) { d3 = 0; if (++d2 == 3) { d2 = 0; if (++d1 == 3) { d1 = 0; ++d0; } } }
        P3 = sel3(mA[0], d0) * sel3(mA[1], d1) * sel3(mA[2], d2) * sel3(mA[3], d3);
    }

    // C/D layout (m89-verified): col = lane&15, row = (lane>>4)*4 + reg
    {
        const int col = l & 15, rgrp = l >> 4;
        #pragma unroll
        for (int r = 0; r < 4; ++r)
            Wred[wv][(rgrp * 4 + r) * 16 + col] = acc[r];
    }
    __syncthreads();

    if (tid < 256) {
        const int row = tid >> 4, cc = tid & 15;
        float Wsum = 0.0f;
        #pragma unroll
        for (int w = 0; w < 8; ++w) Wsum += Wred[w][tid];

        const int bb = tile * 16 + row;
        float xbv = (cc < 8) ? x[(size_t)bb * NI + cc] : (cc == 8 ? 1.0f : 0.0f);
        float p = Wsum * xbv;
        p += __shfl_xor(p, 1);
        p += __shfl_xor(p, 2);
        p += __shfl_xor(p, 4);
        p += __shfl_xor(p, 8);

        if (cc == 0) {
            const float4* yv = (const float4*)(x + (size_t)bb * NI);
            float4 y0 = yv[0], y1 = yv[1];
            float yr[NI] = {y0.x, y0.y, y0.z, y0.w, y1.x, y1.y, y1.z, y1.w};
            float S = 1.0f, Ksum = 0.0f;
            #pragma unroll
            for (int j = 0; j < NI; ++j) {
                float e0 = yr[j] - centers[j * NM + 0];
                float e1 = yr[j] - centers[j * NM + 1];
                float e2 = yr[j] - centers[j * NM + 2];
                float a0 = e0 * e0 * il2[0];
                float a1 = e1 * e1 * il2[1];
                float a2 = e2 * e2 * il2[2];
                S *= exp2f(a0) + exp2f(a1) + exp2f(a2);
                Ksum += fmaxf(fmaxf(a0, a1), a2);
            }
            out[bb] = p * exp2f(Ksum) / (S + 1e-6f);
        }
    }
}

extern "C" void kernel_launch(void* const* d_in, const int* in_sizes, int n_in,
                              void* d_out, int out_size, void* d_ws, size_t ws_size,
                              hipStream_t stream)
{
    const float* x       = (const float*)d_in[0];
    const float* centers = (const float*)d_in[1];
    const float* sigmas  = (const float*)d_in[2];
    const float* cons    = (const float*)d_in[3];
    float* out           = (float*)d_out;
    u32*   Bpack         = (u32*)d_ws;   // NT*64*16 B = 249 KB

    int coop = 1;
    void* args[] = { (void*)&x, (void*)&centers, (void*)&sigmas, (void*)&cons,
                     (void*)&Bpack, (void*)&out, (void*)&coop };
    hipError_t e = hipLaunchCooperativeKernel((const void*)sugeno_fused,
                                              dim3(BATCH / 16), dim3(512),
                                              args, 0, stream);
    if (e != hipSuccess) {
        (void)hipGetLastError();   // clear error state
        sugeno_prep<<<(NT * 64 + 255) / 256, 256, 0, stream>>>(cons, Bpack);
        hipLaunchKernelGGL(sugeno_fused, dim3(BATCH / 16), dim3(512), 0, stream,
                           x, centers, sigmas, cons, Bpack, out, 0);
    }
}

// Round 10
// 26.696 us; speedup vs baseline: 6.7269x; 6.7269x over previous
//
#include <hip/hip_runtime.h>
#include <math.h>
#include <stdint.h>

#define BATCH 8192
#define NI    8
#define NM    3
#define NT    243             // K-steps; step t = digits d0..d4, 27 rules (+5 zero pads)
#define IL2C  (-0.72134752f)  // -0.5*log2(e): mu = exp2(d*d*IL2C/sigma^2)

typedef uint32_t u32;
typedef __fp16 h2    __attribute__((ext_vector_type(2)));
typedef __fp16 f16x8 __attribute__((ext_vector_type(8)));
typedef float  f32x4 __attribute__((ext_vector_type(4)));
typedef u32    u32x4 __attribute__((ext_vector_type(4)));

__device__ __forceinline__ u32 pack2(float a, float b) {
    h2 p = __builtin_amdgcn_cvt_pkrtz(a, b);
    return __builtin_bit_cast(u32, p);
}
__device__ __forceinline__ float sel3(const float* v, int i) {
    return (i == 0) ? v[0] : ((i == 1) ? v[1] : v[2]);
}

// Single kernel: per-wave K-split GEMM with B generated in-loop from cons
// (no prep kernel, no workspace, no inter-block dependency).
// A slot j and B slot j use the SAME (lane,slot)->rule map k = (lane>>4)*8+j,
// rule = t*27 + k (k<27; pads zero) — contraction is slot-permutation-invariant
// (R7/R8-verified, absmax 1.56e-2).
__global__ __launch_bounds__(512, 4) void sugeno_one(
    const float* __restrict__ x,        // [BATCH][8]
    const float* __restrict__ centers,  // [8][3]
    const float* __restrict__ sigmas,   // [3]
    const float* __restrict__ cons,     // [6561][9]
    float* __restrict__ out)            // [BATCH]
{
    __shared__ float Wred[8][256];
    const int tid  = threadIdx.x;
    const int l    = tid & 63;
    const int wv   = tid >> 6;          // 0..7 = K-split
    const int tile = blockIdx.x;
    const int brow = tile * 16 + (l & 15);

    // ---- prologue: memberships (normalized so max rule strength == 1) ----
    const float4* xv = (const float4*)(x + (size_t)brow * NI);
    float4 x0 = xv[0], x1 = xv[1];
    float xr[NI] = {x0.x, x0.y, x0.z, x0.w, x1.x, x1.y, x1.z, x1.w};

    float il2[NM];
    #pragma unroll
    for (int m = 0; m < NM; ++m) {
        float s = sigmas[m];
        il2[m] = IL2C / (s * s);
    }

    float mA[NI][NM];
    #pragma unroll
    for (int j = 0; j < NI; ++j) {
        float d0 = xr[j] - centers[j * NM + 0];
        float d1 = xr[j] - centers[j * NM + 1];
        float d2 = xr[j] - centers[j * NM + 2];
        float a0 = d0 * d0 * il2[0];
        float a1 = d1 * d1 * il2[1];
        float a2 = d2 * d2 * il2[2];
        float Kj = fmaxf(fmaxf(a0, a1), a2);
        mA[j][0] = exp2f(a0 - Kj);
        mA[j][1] = exp2f(a1 - Kj);
        mA[j][2] = exp2f(a2 - Kj);
    }

    // per-lane low-digit products (inputs 5..7), packed f16 pairs
    const int n  = l & 15;
    const int kb = (l >> 4) * 8;
    u32 Lp[4];
    #pragma unroll
    for (int i = 0; i < 4; ++i) {
        float lv[2];
        #pragma unroll
        for (int h = 0; h < 2; ++h) {
            int k = kb + 2 * i + h;
            lv[h] = (k < 27)
                  ? sel3(mA[5], k / 9) * sel3(mA[6], (k % 9) / 3) * sel3(mA[7], k % 3)
                  : 0.0f;
        }
        Lp[i] = pack2(lv[0], lv[1]);
    }

    // K-split bookkeeping
    const int t0     = wv * 30;                 // multiple of 3
    const int ngroup = (wv == 7) ? 11 : 10;     // 243 = 7*30 + 33

    int g3 = t0 / 3;
    int d3 = g3 % 3, d2 = (g3 / 3) % 3, d1 = (g3 / 9) % 3, d0 = g3 / 27;
    float P3 = sel3(mA[0], d0) * sel3(mA[1], d1) * sel3(mA[2], d2) * sel3(mA[3], d3);

    // per-lane B source: cons[(t*27 + kb + j)*9 + n] = cbase[t*243 + j*9]
    const float* __restrict__ cbase = cons + (size_t)(kb * 9 + n);
    const bool nok = (n < 9);

    f32x4 acc = {0.0f, 0.0f, 0.0f, 0.0f};

    for (int g = 0; g < ngroup; ++g) {
        const int tg = t0 + g * 3;
        #pragma unroll
        for (int ph = 0; ph < 3; ++ph) {        // d4 = ph (compile-time)
            const int t = tg + ph;
            // B fragment straight from cons (guarded scattered loads; L1/L2-hit)
            float bf[8];
            #pragma unroll
            for (int j = 0; j < 8; ++j) {
                bool ok = nok && (kb + j < 27);
                bf[j] = ok ? cbase[(size_t)t * 243 + j * 9] : 0.0f;
            }
            u32x4 bw;
            bw[0] = pack2(bf[0], bf[1]);
            bw[1] = pack2(bf[2], bf[3]);
            bw[2] = pack2(bf[4], bf[5]);
            bw[3] = pack2(bf[6], bf[7]);

            // A fragment: U * L (packed f16 muls)
            float U = P3 * mA[4][ph];
            u32 uu = pack2(U, U);
            h2 uh = __builtin_bit_cast(h2, uu);
            u32x4 aw;
            #pragma unroll
            for (int i = 0; i < 4; ++i) {
                h2 prod = __builtin_bit_cast(h2, Lp[i]) * uh;   // v_pk_mul_f16
                aw[i] = __builtin_bit_cast(u32, prod);
            }
            acc = __builtin_amdgcn_mfma_f32_16x16x32_f16(
                      __builtin_bit_cast(f16x8, aw),
                      __builtin_bit_cast(f16x8, bw),
                      acc, 0, 0, 0);
        }
        if (++d3 == 3) { d3 = 0; if (++d2 == 3) { d2 = 0; if (++d1 == 3) { d1 = 0; ++d0; } } }
        P3 = sel3(mA[0], d0) * sel3(mA[1], d1) * sel3(mA[2], d2) * sel3(mA[3], d3);
    }

    // C/D layout (m89-verified): col = lane&15, row = (lane>>4)*4 + reg
    {
        const int col = l & 15, rgrp = l >> 4;
        #pragma unroll
        for (int r = 0; r < 4; ++r)
            Wred[wv][(rgrp * 4 + r) * 16 + col] = acc[r];
    }
    __syncthreads();

    // combine K-splits + numerator dot + exact denominator
    if (tid < 256) {
        const int row = tid >> 4, cc = tid & 15;
        float Wsum = 0.0f;
        #pragma unroll
        for (int w = 0; w < 8; ++w) Wsum += Wred[w][tid];

        const int bb = tile * 16 + row;
        float xbv = (cc < 8) ? x[(size_t)bb * NI + cc] : (cc == 8 ? 1.0f : 0.0f);
        float p = Wsum * xbv;
        p += __shfl_xor(p, 1);
        p += __shfl_xor(p, 2);
        p += __shfl_xor(p, 4);
        p += __shfl_xor(p, 8);

        if (cc == 0) {
            const float4* yv = (const float4*)(x + (size_t)bb * NI);
            float4 y0 = yv[0], y1 = yv[1];
            float yr[NI] = {y0.x, y0.y, y0.z, y0.w, y1.x, y1.y, y1.z, y1.w};
            float S = 1.0f, Ksum = 0.0f;
            #pragma unroll
            for (int j = 0; j < NI; ++j) {
                float e0 = yr[j] - centers[j * NM + 0];
                float e1 = yr[j] - centers[j * NM + 1];
                float e2 = yr[j] - centers[j * NM + 2];
                float a0 = e0 * e0 * il2[0];
                float a1 = e1 * e1 * il2[1];
                float a2 = e2 * e2 * il2[2];
                S *= exp2f(a0) + exp2f(a1) + exp2f(a2);
                Ksum += fmaxf(fmaxf(a0, a1), a2);
            }
            out[bb] = p * exp2f(Ksum) / (S + 1e-6f);
        }
    }
}

extern "C" void kernel_launch(void* const* d_in, const int* in_sizes, int n_in,
                              void* d_out, int out_size, void* d_ws, size_t ws_size,
                              hipStream_t stream)
{
    const float* x       = (const float*)d_in[0];
    const float* centers = (const float*)d_in[1];
    const float* sigmas  = (const float*)d_in[2];
    const float* cons    = (const float*)d_in[3];
    float* out           = (float*)d_out;

    sugeno_one<<<BATCH / 16, 512, 0, stream>>>(x, centers, sigmas, cons, out);
}